// Round 7
// baseline (162.477 us; speedup 1.0000x reference)
//
#include <hip/hip_runtime.h>

#define BB 8
#define CC 256
#define HH 64
#define WW 64
#define RED 64
#define HW 4096   // HH*WW
#define AST 72    // xs bf16 row stride ([px][c] layout, 16B-aligned rows)
#define LSH 72    // bf16 LDS row stride (x1 / res planes in invol_dw)
#define WLS 10    // wl f32 stride (10c mod 32 -> 16 banks, 2-way = free)

typedef __attribute__((ext_vector_type(8))) short s8v;   // 8 bf16 (4 VGPRs)
typedef __attribute__((ext_vector_type(4))) float f4v;   // MFMA accumulator

__device__ __forceinline__ unsigned short f2bf(float f) {  // RNE f32->bf16
    unsigned u = __float_as_uint(f);
    u += 0x7fff + ((u >> 16) & 1);
    return (unsigned short)(u >> 16);
}
__device__ __forceinline__ float b2f(unsigned short u) {   // bf16->f32
    return __uint_as_float(((unsigned)u) << 16);
}

// ---- build w_red in B-fragment order (bf16) ----
// wtf[e], e = ((kbg*4 + nt)*64 + lane)*8 + j  holds  B[k][n] = w_red[o=n][c=k]
// with n = nt*16 + (lane&15), k = kbg*32 + (lane>>4)*8 + j.  32 KB, L2-resident.
__global__ __launch_bounds__(256) void build_wtf(const float* __restrict__ w_red,
                                                 unsigned short* __restrict__ wtf) {
    int e = blockIdx.x * 256 + threadIdx.x;      // 64 blocks -> 16384
    int j = e & 7, l = (e >> 3) & 63, nt = (e >> 9) & 3, kbg = e >> 11;
    int o = nt * 16 + (l & 15);
    int c = kbg * 32 + ((l >> 4) & 3) * 8 + j;
    wtf[e] = f2bf(w_red[o * CC + c]);
}

// ---- fused dwconv1 + involution-kernel-generation (quarter-row blocks) ----
// R5: R3 counters proved this kernel latency-bound (all pipes <20%); R4's
// 2->4 blocks/CU bought ~14us.  Push the same lever to its limit:
//  * 16-px tiles: grid (256,8) = 2048 blocks = 8 blocks/CU x 4 waves
//    = 32 waves/CU (hw max).  LDS 14.5 KB/block (8x14.5 = 116 <= 160).
//  * MFMA tiling: M=16px (single A-tile, m0=0), N=64o; wave wv owns
//    nt=wv.  Fragment index formulas byte-identical to verified code.
//  * w_in/b_in staged once in LDS wl[c*10+{0..8,9}] (conflict-free).
// Two-barrier k-loop shape preserved [R12/R13: do not re-pipeline].
__global__ __launch_bounds__(256, 8) void dw_kern(const float* __restrict__ x,
                                                  const float* __restrict__ w_in,
                                                  const float* __restrict__ b_in,
                                                  const unsigned short* __restrict__ wtf,
                                                  const float* __restrict__ b_red,
                                                  const float* __restrict__ w_span,  // [9][64]
                                                  const float* __restrict__ b_span,
                                                  float* __restrict__ kern,
                                                  unsigned short* __restrict__ x1g) {
    alignas(16) __shared__ char smem[4608 + 10240];      // 14.5 KB
    unsigned short* xs = (unsigned short*)smem;          // [16px][AST] bf16 (2.3 KB)
    float* r_lds = (float*)smem;                         // [64o][17] f32, aliases xs (dead)
    float* wl    = (float*)(smem + 4608);                // [256c][10] w_in+b_in staging
    float* part  = (float*)(smem + 4608);                // [16og][9][16px], aliases wl (dead)

    const int t    = threadIdx.x;
    const int bx   = blockIdx.x;
    const int band = bx & 7;                     // XCD band swizzle
    const int idx  = bx >> 3;                    // 0..31
    const int h    = band * 8 + (idx >> 2);      // 8 consecutive h per XCD band
    const int qh   = idx & 3;                    // which 16-px quarter of the row
    const int b    = blockIdx.y;
    const int l  = t & 63;                       // lane
    const int wv = t >> 6;                       // wave 0..3 (= nt tile)
    // phase-A mapping: 4 col-quads x 64 channel-rows
    const int q  = t & 3;
    const int pl = q << 2;                       // local px 0,4,8,12
    const int wg = (qh << 4) | pl;               // global w 0..60
    const int cr = t >> 2;                       // 0..63 (channel within chunk)

    // stage w_in [256][9] + b_in [256] -> wl[c*10 + {0..8, 9}] (one-time)
    #pragma unroll
    for (int j = 0; j < 9; j++) {
        int i = j * 256 + t;                     // coalesced read of 2304 floats
        wl[(i / 9) * WLS + (i % 9)] = w_in[i];
    }
    wl[t * WLS + 9] = b_in[t];

    float4 pv[3]; float plf[3], prt[3];          // x-row prefetch regs

    auto loadX = [&](int c0) {
        const int cc = c0 + cr;
        const float* xp = x + ((size_t)(b * CC + cc)) * HW;
        #pragma unroll
        for (int ky = 0; ky < 3; ky++) {
            int hh = h + ky - 1;
            if (hh < 0 || hh >= HH) {            // block-uniform branch
                pv[ky] = make_float4(0.f, 0.f, 0.f, 0.f);
                plf[ky] = 0.f; prt[ky] = 0.f;
                continue;
            }
            const float* row = xp + hh * WW + wg;
            pv[ky]  = *(const float4*)row;
            plf[ky] = (wg > 0)      ? row[-1] : 0.f;
            prt[ky] = (wg + 4 < WW) ? row[4]  : 0.f;
        }
    };
    auto computeA = [&](int c0) {                // dwconv from regs -> bf16 xs + x1g
        const int cc = c0 + cr;
        const float* wp = wl + cc * WLS;         // weights from LDS (staged once)
        const float bb = wp[9];
        float4 a4 = make_float4(bb, bb, bb, bb);
        #pragma unroll
        for (int ky = 0; ky < 3; ky++) {
            float4 v = pv[ky];
            float lf = plf[ky], rt = prt[ky];
            float k0 = wp[ky * 3 + 0], k1 = wp[ky * 3 + 1], k2 = wp[ky * 3 + 2];
            a4.x = fmaf(k0, lf,  a4.x); a4.y = fmaf(k0, v.x, a4.y);
            a4.z = fmaf(k0, v.y, a4.z); a4.w = fmaf(k0, v.z, a4.w);
            a4.x = fmaf(k1, v.x, a4.x); a4.y = fmaf(k1, v.y, a4.y);
            a4.z = fmaf(k1, v.z, a4.z); a4.w = fmaf(k1, v.w, a4.w);
            a4.x = fmaf(k2, v.y, a4.x); a4.y = fmaf(k2, v.z, a4.y);
            a4.z = fmaf(k2, v.w, a4.z); a4.w = fmaf(k2, rt,  a4.w);
        }
        ushort4 pk;
        pk.x = f2bf(a4.x); pk.y = f2bf(a4.y);
        pk.z = f2bf(a4.z); pk.w = f2bf(a4.w);
        xs[(pl + 0) * AST + cr] = pk.x;          // [px][c] for A-frag reads
        xs[(pl + 1) * AST + cr] = pk.y;
        xs[(pl + 2) * AST + cr] = pk.z;
        xs[(pl + 3) * AST + cr] = pk.w;
        // bf16 x1 handoff for kernel 2
        *(ushort4*)(x1g + ((size_t)(b * CC + cc)) * HW + h * WW + wg) = pk;
    };

    s8v bfr[2];                                  // B-frags [kb] for current chunk
    auto loadB = [&](int k) {
        #pragma unroll
        for (int kb = 0; kb < 2; kb++) {
            int kbg = (k << 1) + kb;
            bfr[kb] = *(const s8v*)(wtf + (((kbg * 4 + wv) * 64 + l) << 3));
        }
    };

    f4v acc = {0.f, 0.f, 0.f, 0.f};

    loadX(0); loadB(0);
    __syncthreads();                             // wl staged before computeA reads it
    for (int k = 0; k < 4; k++) {
        computeA(k << 6);                        // regs -> xs (bf16) + x1g
        if (k < 3) loadX((k + 1) << 6);          // VMEM issue for next chunk
        __syncthreads();
        // phase B: 2 A-frag ds_read_b128 + 2 MFMA per wave
        #pragma unroll
        for (int kb = 0; kb < 2; kb++) {
            const unsigned short* ap =
                xs + (l & 15) * AST + (kb << 5) + ((l >> 4) & 3) * 8;
            s8v av = *(const s8v*)ap;
            acc = __builtin_amdgcn_mfma_f32_16x16x32_bf16(av, bfr[kb], acc, 0, 0, 0);
        }
        if (k < 3) loadB(k + 1);
        __syncthreads();                         // xs consumed; safe to overwrite
    }

    // C-frags -> r_lds[o][17] (aliases dead xs); row = px, col = o
    {
        int o = (wv << 4) + (l & 15);
        int pxr = ((l >> 4) & 3) * 4;            // row = (lane>>4)*4 + i
        #pragma unroll
        for (int i = 0; i < 4; i++)
            r_lds[o * 17 + pxr + i] = acc[i];
    }
    __syncthreads();

    // epilogue: relu + span contraction; og = t>>4 (16 o-groups of 4)
    const int px = t & 15;
    const int og = t >> 4;                       // 0..15
    const int o0 = og << 2;
    float kk[9];
    #pragma unroll
    for (int j = 0; j < 9; j++) kk[j] = 0.f;
    #pragma unroll
    for (int i = 0; i < 4; i++) {
        float r = fmaxf(r_lds[(o0 + i) * 17 + px] + b_red[o0 + i], 0.f);
        #pragma unroll
        for (int j = 0; j < 9; j++) kk[j] = fmaf(w_span[j * RED + o0 + i], r, kk[j]);
    }
    __syncthreads();                             // all wl reads long done; r_lds reads done
    #pragma unroll
    for (int j = 0; j < 9; j++) part[(og * 9 + j) * 16 + px] = kk[j];
    __syncthreads();

    // cross-o-group reduction: thread (px, jj), jj = t>>4 (0..8 for t<144)
    if (t < 144) {
        const int jj = t >> 4;
        float s = b_span[jj];
        #pragma unroll
        for (int g = 0; g < 16; g++) s += part[(g * 9 + jj) * 16 + px];
        kern[(size_t)b * 9 * HW + jj * HW + h * WW + (qh << 4) + px] = s;
    }
}

// ---- involution-apply + dwconv2, consuming precomputed bf16 x1 ----
// One block per (c,b) plane: 256 threads / 4 waves.  R5: res plane stored
// as bf16 -> LDS 18 KB -> 8 blocks/CU (was 6 at 26.6 KB).  Precision: res
// quantization adds ~2e-4 absolute after dwconv2 (threshold 3.6e-3).
__global__ __launch_bounds__(256, 8) void invol_dw(const unsigned short* __restrict__ x1g,
                                                   const float* __restrict__ kern,
                                                   const float* __restrict__ w_out,
                                                   const float* __restrict__ b_out,
                                                   float* __restrict__ out) {
    __shared__ unsigned short x1s[HH * LSH];     // bf16 x1 plane (9.2 KB)
    __shared__ unsigned short res[HH * LSH];     // bf16 involution result (9.2 KB)
    const int t  = threadIdx.x;
    const int q  = t & 15;
    const int w0 = q << 2;
    const int r  = t >> 4;                       // 0..15
    const int c = blockIdx.x, b = blockIdx.y;

    // stage x1 plane: 4096 bf16, fully contiguous (16 shorts/thread)
    {
        const unsigned short* xp = x1g + ((size_t)(b * CC + c)) * HW;
        const int hl = t >> 2;                   // 0..63
        const int wl2 = (t & 3) << 4;            // 0,16,32,48
        *(s8v*)&x1s[hl * LSH + wl2]     = *(const s8v*)(xp + hl * WW + wl2);
        *(s8v*)&x1s[hl * LSH + wl2 + 8] = *(const s8v*)(xp + hl * WW + wl2 + 8);
    }
    __syncthreads();

    // involution apply: res[h,w] = sum_k kern[k,h,w] * x1[h+dy, w+dx]
    const float* kp = kern + (size_t)b * 9 * HW;
    #pragma unroll
    for (int i = 0; i < 4; i++) {
        int h  = r + (i << 4);
        int hw = h * WW + w0;
        float4 acc = make_float4(0.f, 0.f, 0.f, 0.f);
        #pragma unroll
        for (int ky = 0; ky < 3; ky++) {
            int hh = h + ky - 1;
            if (hh < 0 || hh >= HH) continue;
            const unsigned short* row = &x1s[hh * LSH + w0];
            float vx = b2f(row[0]), vy = b2f(row[1]);
            float vz = b2f(row[2]), vw = b2f(row[3]);
            float lf = (w0 > 0)      ? b2f(row[-1]) : 0.f;
            float rt = (w0 + 4 < WW) ? b2f(row[4])  : 0.f;
            float4 k0 = *(const float4*)(kp + (ky * 3 + 0) * HW + hw);
            float4 k1 = *(const float4*)(kp + (ky * 3 + 1) * HW + hw);
            float4 k2 = *(const float4*)(kp + (ky * 3 + 2) * HW + hw);
            acc.x = fmaf(k0.x, lf, acc.x); acc.y = fmaf(k0.y, vx, acc.y);
            acc.z = fmaf(k0.z, vy, acc.z); acc.w = fmaf(k0.w, vz, acc.w);
            acc.x = fmaf(k1.x, vx, acc.x); acc.y = fmaf(k1.y, vy, acc.y);
            acc.z = fmaf(k1.z, vz, acc.z); acc.w = fmaf(k1.w, vw, acc.w);
            acc.x = fmaf(k2.x, vy, acc.x); acc.y = fmaf(k2.y, vz, acc.y);
            acc.z = fmaf(k2.z, vw, acc.z); acc.w = fmaf(k2.w, rt, acc.w);
        }
        ushort4 pk;
        pk.x = f2bf(acc.x); pk.y = f2bf(acc.y);
        pk.z = f2bf(acc.z); pk.w = f2bf(acc.w);
        *(ushort4*)&res[h * LSH + w0] = pk;      // bf16 res
    }
    __syncthreads();

    // dwconv2 from res (bf16 LDS), write final output
    const float* wp = w_out + c * 9;             // block-uniform -> s_load
    const float bb = b_out[c];
    float* op = out + ((size_t)(b * CC + c)) * HW;
    #pragma unroll
    for (int i = 0; i < 4; i++) {
        int h = r + (i << 4);
        float4 acc = make_float4(bb, bb, bb, bb);
        #pragma unroll
        for (int ky = 0; ky < 3; ky++) {
            int hh = h + ky - 1;
            if (hh < 0 || hh >= HH) continue;
            const unsigned short* row = &res[hh * LSH + w0];
            float vx = b2f(row[0]), vy = b2f(row[1]);
            float vz = b2f(row[2]), vw = b2f(row[3]);
            float lf = (w0 > 0)      ? b2f(row[-1]) : 0.f;
            float rt = (w0 + 4 < WW) ? b2f(row[4])  : 0.f;
            float k0 = wp[ky * 3 + 0], k1 = wp[ky * 3 + 1], k2 = wp[ky * 3 + 2];
            acc.x = fmaf(k0, lf, acc.x); acc.y = fmaf(k0, vx, acc.y);
            acc.z = fmaf(k0, vy, acc.z); acc.w = fmaf(k0, vz, acc.w);
            acc.x = fmaf(k1, vx, acc.x); acc.y = fmaf(k1, vy, acc.y);
            acc.z = fmaf(k1, vz, acc.z); acc.w = fmaf(k1, vw, acc.w);
            acc.x = fmaf(k2, vy, acc.x); acc.y = fmaf(k2, vz, acc.y);
            acc.z = fmaf(k2, vw, acc.z); acc.w = fmaf(k2, rt, acc.w);
        }
        *(float4*)(op + h * WW + w0) = acc;
    }
}

extern "C" void kernel_launch(void* const* d_in, const int* in_sizes, int n_in,
                              void* d_out, int out_size, void* d_ws, size_t ws_size,
                              hipStream_t stream) {
    const float* x      = (const float*)d_in[0];
    const float* w_in   = (const float*)d_in[1];
    const float* b_in   = (const float*)d_in[2];
    const float* w_red  = (const float*)d_in[3];
    const float* b_red  = (const float*)d_in[4];
    const float* w_span = (const float*)d_in[5];
    const float* b_span = (const float*)d_in[6];
    const float* w_out  = (const float*)d_in[7];
    const float* b_out  = (const float*)d_in[8];
    float* out = (float*)d_out;

    float* kern = (float*)d_ws;                              // 1.18 MB
    unsigned short* x1g = (unsigned short*)(kern + (size_t)BB * 9 * HW); // 16.8 MB bf16
    unsigned short* wtf = x1g + (size_t)BB * CC * HW;        // 32 KB bf16

    build_wtf<<<64, 256, 0, stream>>>(w_red, wtf);
    dw_kern<<<dim3(256, BB), 256, 0, stream>>>(x, w_in, b_in, wtf, b_red,
                                               w_span, b_span, kern, x1g);
    invol_dw<<<dim3(CC, BB), 256, 0, stream>>>(x1g, kern, w_out, b_out, out);
}

// Round 8
// 143.009 us; speedup vs baseline: 1.1361x; 1.1361x over previous
//
#include <hip/hip_runtime.h>

#define BB 8
#define CC 256
#define HH 64
#define WW 64
#define RED 64
#define HW 4096   // HH*WW
#define AST 72    // xs bf16 row stride ([px][c] layout, 16B-aligned rows)
#define XST 40    // xst bf16 row stride ([c][px], 16B-aligned rows for b128)
#define LSH 72    // bf16 LDS row stride (x1 / res planes in invol_dw)
#define WLS 10    // wl f32 stride

typedef __attribute__((ext_vector_type(8))) short s8v;   // 8 bf16 (4 VGPRs)
typedef __attribute__((ext_vector_type(4))) float f4v;   // MFMA accumulator

__device__ __forceinline__ unsigned short f2bf(float f) {  // RNE f32->bf16
    unsigned u = __float_as_uint(f);
    u += 0x7fff + ((u >> 16) & 1);
    return (unsigned short)(u >> 16);
}
__device__ __forceinline__ float b2f(unsigned short u) {   // bf16->f32
    return __uint_as_float(((unsigned)u) << 16);
}

// ---- build w_red in B-fragment order (bf16) ----
__global__ __launch_bounds__(256) void build_wtf(const float* __restrict__ w_red,
                                                 unsigned short* __restrict__ wtf) {
    int e = blockIdx.x * 256 + threadIdx.x;      // 64 blocks -> 16384
    int j = e & 7, l = (e >> 3) & 63, nt = (e >> 9) & 3, kbg = e >> 11;
    int o = nt * 16 + (l & 15);
    int c = kbg * 32 + ((l >> 4) & 3) * 8 + j;
    wtf[e] = f2bf(w_red[o * CC + c]);
}

// ---- fused dwconv1 + involution-kernel-generation (half-row blocks) ----
// R8: back to the R4 geometry (best measured; R5's 8-blk/CU quartering
// REGRESSED: Occ 59% but dur 53.7us -- not concurrency-starved).  R7
// counters (VALU 13.6%, MFMA 0.7%, HBM 17%, Occ 59%: nothing busy) point
// at VMEM address-processing as the shared serializer (~90 gather-heavy
// VMEM instrs/thread; WRITE_SIZE 46MB vs 18 logical).  R8 cuts that:
//  * halo via __shfl_up/down (12 scalar gathers/chunk -> 1 masked dword)
//  * x1g via xst[c][px] LDS transpose; ONE deferred wave-contiguous
//    16ch x 64B store pass at kernel end (no in-loop store drains)
//  * epilogue consts (w_span/b_red/b_span) staged in LDS once
// MFMA fragment formulas + two-barrier k-loop = R4 verified shape
// [R12/R13: do not re-pipeline].
__global__ __launch_bounds__(256, 4) void dw_kern(const float* __restrict__ x,
                                                  const float* __restrict__ w_in,
                                                  const float* __restrict__ b_in,
                                                  const unsigned short* __restrict__ wtf,
                                                  const float* __restrict__ b_red,
                                                  const float* __restrict__ w_span,  // [9][64]
                                                  const float* __restrict__ b_span,
                                                  float* __restrict__ kern,
                                                  unsigned short* __restrict__ x1g) {
    // regions: [0,8448) xs|r_lds, [8448,13568) xst, [13568,23808) wl|part,
    //          [23808,26448) consts.  ~25.8 KB -> 4 blocks/CU (VGPR-capped).
    alignas(16) __shared__ char smem[8448 + 5120 + 10240 + 2640];
    unsigned short* xs  = (unsigned short*)smem;           // [32px][AST] bf16
    float* r_lds        = (float*)smem;                    // [64o][33] f32, aliases xs
    unsigned short* xst = (unsigned short*)(smem + 8448);  // [64c][XST] bf16
    float* wl           = (float*)(smem + 13568);          // [256c][10] w_in+b_in
    float* part         = (float*)(smem + 13568);          // [8og][9][32px], aliases wl
    float* ws_l         = (float*)(smem + 23808);          // [576] w_span
    float* br_l         = ws_l + 576;                      // [64] b_red
    float* bs_l         = br_l + 64;                       // [9] b_span

    const int t    = threadIdx.x;
    const int bx   = blockIdx.x;
    const int band = bx & 7;                     // XCD band swizzle
    const int idx  = bx >> 3;                    // 0..15
    const int h    = band * 8 + (idx >> 1);      // 8 consecutive h per XCD band
    const int wh   = idx & 1;                    // which 32-px half of the row
    const int b    = blockIdx.y;
    const int l  = t & 63;                       // lane
    const int wv = t >> 6;                       // wave 0..3
    const int mt = wv & 1, nh = wv >> 1;
    const int m0 = mt << 4;
    // phase-A mapping: 8 col-quads x 32 channel-rows
    const int q  = t & 7;
    const int pl = q << 2;                       // local px 0..28
    const int wg = (wh << 5) | pl;               // global w 0..60
    const int cr = t >> 3;                       // 0..31

    // one-time staging: w_in/b_in -> wl; epilogue consts -> ws_l/br_l/bs_l
    #pragma unroll
    for (int j = 0; j < 9; j++) {
        int i = j * 256 + t;                     // coalesced read of 2304 floats
        wl[(i / 9) * WLS + (i % 9)] = w_in[i];
    }
    wl[t * WLS + 9] = b_in[t];
    ws_l[t]       = w_span[t];
    ws_l[256 + t] = w_span[256 + t];
    if (t < 64) { ws_l[512 + t] = w_span[512 + t]; br_l[t] = b_red[t]; }
    if (t < 9)  bs_l[t] = b_span[t];

    float4 pv[2][3]; float phal[2][3];           // x-row prefetch + single halo elem

    auto loadX = [&](int c0) {
        #pragma unroll
        for (int s = 0; s < 2; s++) {
            const int cc = c0 + s * 32 + cr;
            const float* xp = x + ((size_t)(b * CC + cc)) * HW;
            #pragma unroll
            for (int ky = 0; ky < 3; ky++) {
                int hh = h + ky - 1;
                if (hh < 0 || hh >= HH) {        // block-uniform branch
                    pv[s][ky] = make_float4(0.f, 0.f, 0.f, 0.f);
                    phal[s][ky] = 0.f;
                    continue;
                }
                const float* row = xp + hh * WW + wg;
                pv[s][ky] = *(const float4*)row;
                float hv = 0.f;                  // edge-lane halo only:
                if (q == 0) { if (wg > 0) hv = row[-1]; }          // active iff wh==1
                else if (q == 7) { if (wg + 4 < WW) hv = row[4]; } // active iff wh==0
                phal[s][ky] = hv;
            }
        }
    };
    auto computeA = [&](int c0) {                // dwconv from regs -> bf16 xs + xst
        #pragma unroll
        for (int s = 0; s < 2; s++) {
            const int cl = s * 32 + cr;
            const int cc = c0 + cl;
            const float* wp = wl + cc * WLS;     // weights from LDS (staged once)
            const float bb = wp[9];
            float4 a4 = make_float4(bb, bb, bb, bb);
            #pragma unroll
            for (int ky = 0; ky < 3; ky++) {
                float4 v = pv[s][ky];
                float lf = __shfl_up(v.w, 1);    // neighbor quad's last px
                if (q == 0) lf = phal[s][ky];
                float rt = __shfl_down(v.x, 1);  // neighbor quad's first px
                if (q == 7) rt = phal[s][ky];
                float k0 = wp[ky * 3 + 0], k1 = wp[ky * 3 + 1], k2 = wp[ky * 3 + 2];
                a4.x = fmaf(k0, lf,  a4.x); a4.y = fmaf(k0, v.x, a4.y);
                a4.z = fmaf(k0, v.y, a4.z); a4.w = fmaf(k0, v.z, a4.w);
                a4.x = fmaf(k1, v.x, a4.x); a4.y = fmaf(k1, v.y, a4.y);
                a4.z = fmaf(k1, v.z, a4.z); a4.w = fmaf(k1, v.w, a4.w);
                a4.x = fmaf(k2, v.y, a4.x); a4.y = fmaf(k2, v.z, a4.y);
                a4.z = fmaf(k2, v.w, a4.z); a4.w = fmaf(k2, rt,  a4.w);
            }
            ushort4 pk;
            pk.x = f2bf(a4.x); pk.y = f2bf(a4.y);
            pk.z = f2bf(a4.z); pk.w = f2bf(a4.w);
            xs[(pl + 0) * AST + cl] = pk.x;      // [px][c] for A-frag reads
            xs[(pl + 1) * AST + cl] = pk.y;
            xs[(pl + 2) * AST + cl] = pk.z;
            xs[(pl + 3) * AST + cl] = pk.w;
            *(ushort4*)&xst[cl * XST + pl] = pk; // [c][px] for coalesced x1g store
        }
    };

    s8v bfr[2][2];                               // B-frags [kb][ntl] for current chunk
    auto loadB = [&](int k) {
        #pragma unroll
        for (int kb = 0; kb < 2; kb++)
            #pragma unroll
            for (int ntl = 0; ntl < 2; ntl++) {
                int nt = (nh << 1) + ntl;
                int kbg = (k << 1) + kb;
                bfr[kb][ntl] = *(const s8v*)(wtf + (((kbg * 4 + nt) * 64 + l) << 3));
            }
    };

    f4v acc[2] = {{0.f, 0.f, 0.f, 0.f}, {0.f, 0.f, 0.f, 0.f}};
    int4 x1r[4];                                 // deferred x1g data (16B x 4 chunks)
    const int c2  = t >> 2;                      // x1g-store channel 0..63
    const int px2 = (t & 3) << 3;                // x1g-store px 0,8,16,24

    loadX(0); loadB(0);
    __syncthreads();                             // wl/consts staged
    for (int k = 0; k < 4; k++) {
        computeA(k << 6);                        // regs -> xs + xst (bf16)
        if (k < 3) loadX((k + 1) << 6);          // VMEM issue for next chunk
        __syncthreads();
        // phase B: 2 A-frag ds_read_b128 + 4 MFMA per wave
        #pragma unroll
        for (int kb = 0; kb < 2; kb++) {
            const unsigned short* ap =
                xs + (m0 + (l & 15)) * AST + (kb << 5) + ((l >> 4) & 3) * 8;
            s8v av = *(const s8v*)ap;
            #pragma unroll
            for (int ntl = 0; ntl < 2; ntl++)
                acc[ntl] = __builtin_amdgcn_mfma_f32_16x16x32_bf16(
                    av, bfr[kb][ntl], acc[ntl], 0, 0, 0);
        }
        x1r[k] = *(const int4*)&xst[c2 * XST + px2];  // transpose read (xst stable here)
        if (k < 3) loadB(k + 1);
        __syncthreads();                         // xs/xst consumed; safe to overwrite
    }

    // C-frags -> r_lds[o][33] (aliases dead xs)
    #pragma unroll
    for (int ntl = 0; ntl < 2; ntl++) {
        int o = ((nh << 1) + ntl) * 16 + (l & 15);
        int pxr = m0 + ((l >> 4) & 3) * 4;       // row = (lane>>4)*4 + i
        #pragma unroll
        for (int i = 0; i < 4; i++)
            r_lds[o * 33 + pxr + i] = acc[ntl][i];
    }
    __syncthreads();

    // epilogue: relu + span contraction (consts from LDS); og = t>>5
    const int px = t & 31;
    const int og = t >> 5;                       // 0..7
    const int o0 = og << 3;
    float kk[9];
    #pragma unroll
    for (int j = 0; j < 9; j++) kk[j] = 0.f;
    #pragma unroll
    for (int i = 0; i < 8; i++) {
        float r = fmaxf(r_lds[(o0 + i) * 33 + px] + br_l[o0 + i], 0.f);
        #pragma unroll
        for (int j = 0; j < 9; j++) kk[j] = fmaf(ws_l[j * 64 + o0 + i], r, kk[j]);
    }
    __syncthreads();                             // wl dead -> part may overwrite
    #pragma unroll
    for (int j = 0; j < 9; j++) part[(og * 9 + j) * 32 + px] = kk[j];
    __syncthreads();

    // cross-o-group reduction: thread (px, jj) sums 8 partials for kern[jj]
    float* kp = kern + (size_t)b * 9 * HW + h * WW + (wh << 5) + px;
    const int jj = t >> 5;                       // 0..7
    {
        float s = bs_l[jj];
        #pragma unroll
        for (int g = 0; g < 8; g++) s += part[(g * 9 + jj) * 32 + px];
        kp[jj * HW] = s;
    }
    if (t < 32) {                                // j = 8 by lanes 0..31
        float s = bs_l[8];
        #pragma unroll
        for (int g = 0; g < 8; g++) s += part[(g * 9 + 8) * 32 + px];
        kp[8 * HW] = s;
    }

    // deferred x1g stores: per k, wave covers 16 channels x 64B full lines
    #pragma unroll
    for (int k = 0; k < 4; k++) {
        unsigned short* dst = x1g + ((size_t)(b * CC + (k << 6) + c2)) * HW
                            + h * WW + (wh << 5) + px2;
        *(int4*)dst = x1r[k];
    }
}

// ---- involution-apply + dwconv2, consuming precomputed bf16 x1 ----
// [Unchanged from R7 -- passed.]
__global__ __launch_bounds__(256, 8) void invol_dw(const unsigned short* __restrict__ x1g,
                                                   const float* __restrict__ kern,
                                                   const float* __restrict__ w_out,
                                                   const float* __restrict__ b_out,
                                                   float* __restrict__ out) {
    __shared__ unsigned short x1s[HH * LSH];     // bf16 x1 plane (9.2 KB)
    __shared__ unsigned short res[HH * LSH];     // bf16 involution result (9.2 KB)
    const int t  = threadIdx.x;
    const int q  = t & 15;
    const int w0 = q << 2;
    const int r  = t >> 4;                       // 0..15
    const int c = blockIdx.x, b = blockIdx.y;

    {
        const unsigned short* xp = x1g + ((size_t)(b * CC + c)) * HW;
        const int hl = t >> 2;                   // 0..63
        const int wl2 = (t & 3) << 4;            // 0,16,32,48
        *(s8v*)&x1s[hl * LSH + wl2]     = *(const s8v*)(xp + hl * WW + wl2);
        *(s8v*)&x1s[hl * LSH + wl2 + 8] = *(const s8v*)(xp + hl * WW + wl2 + 8);
    }
    __syncthreads();

    const float* kp = kern + (size_t)b * 9 * HW;
    #pragma unroll
    for (int i = 0; i < 4; i++) {
        int h  = r + (i << 4);
        int hw = h * WW + w0;
        float4 acc = make_float4(0.f, 0.f, 0.f, 0.f);
        #pragma unroll
        for (int ky = 0; ky < 3; ky++) {
            int hh = h + ky - 1;
            if (hh < 0 || hh >= HH) continue;
            const unsigned short* row = &x1s[hh * LSH + w0];
            float vx = b2f(row[0]), vy = b2f(row[1]);
            float vz = b2f(row[2]), vw = b2f(row[3]);
            float lf = (w0 > 0)      ? b2f(row[-1]) : 0.f;
            float rt = (w0 + 4 < WW) ? b2f(row[4])  : 0.f;
            float4 k0 = *(const float4*)(kp + (ky * 3 + 0) * HW + hw);
            float4 k1 = *(const float4*)(kp + (ky * 3 + 1) * HW + hw);
            float4 k2 = *(const float4*)(kp + (ky * 3 + 2) * HW + hw);
            acc.x = fmaf(k0.x, lf, acc.x); acc.y = fmaf(k0.y, vx, acc.y);
            acc.z = fmaf(k0.z, vy, acc.z); acc.w = fmaf(k0.w, vz, acc.w);
            acc.x = fmaf(k1.x, vx, acc.x); acc.y = fmaf(k1.y, vy, acc.y);
            acc.z = fmaf(k1.z, vz, acc.z); acc.w = fmaf(k1.w, vw, acc.w);
            acc.x = fmaf(k2.x, vy, acc.x); acc.y = fmaf(k2.y, vz, acc.y);
            acc.z = fmaf(k2.z, vw, acc.z); acc.w = fmaf(k2.w, rt, acc.w);
        }
        ushort4 pk;
        pk.x = f2bf(acc.x); pk.y = f2bf(acc.y);
        pk.z = f2bf(acc.z); pk.w = f2bf(acc.w);
        *(ushort4*)&res[h * LSH + w0] = pk;      // bf16 res
    }
    __syncthreads();

    const float* wp = w_out + c * 9;             // block-uniform -> s_load
    const float bb = b_out[c];
    float* op = out + ((size_t)(b * CC + c)) * HW;
    #pragma unroll
    for (int i = 0; i < 4; i++) {
        int h = r + (i << 4);
        float4 acc = make_float4(bb, bb, bb, bb);
        #pragma unroll
        for (int ky = 0; ky < 3; ky++) {
            int hh = h + ky - 1;
            if (hh < 0 || hh >= HH) continue;
            const unsigned short* row = &res[hh * LSH + w0];
            float vx = b2f(row[0]), vy = b2f(row[1]);
            float vz = b2f(row[2]), vw = b2f(row[3]);
            float lf = (w0 > 0)      ? b2f(row[-1]) : 0.f;
            float rt = (w0 + 4 < WW) ? b2f(row[4])  : 0.f;
            float k0 = wp[ky * 3 + 0], k1 = wp[ky * 3 + 1], k2 = wp[ky * 3 + 2];
            acc.x = fmaf(k0, lf, acc.x); acc.y = fmaf(k0, vx, acc.y);
            acc.z = fmaf(k0, vy, acc.z); acc.w = fmaf(k0, vz, acc.w);
            acc.x = fmaf(k1, vx, acc.x); acc.y = fmaf(k1, vy, acc.y);
            acc.z = fmaf(k1, vz, acc.z); acc.w = fmaf(k1, vw, acc.w);
            acc.x = fmaf(k2, vy, acc.x); acc.y = fmaf(k2, vz, acc.y);
            acc.z = fmaf(k2, vw, acc.z); acc.w = fmaf(k2, rt, acc.w);
        }
        *(float4*)(op + h * WW + w0) = acc;
    }
}

extern "C" void kernel_launch(void* const* d_in, const int* in_sizes, int n_in,
                              void* d_out, int out_size, void* d_ws, size_t ws_size,
                              hipStream_t stream) {
    const float* x      = (const float*)d_in[0];
    const float* w_in   = (const float*)d_in[1];
    const float* b_in   = (const float*)d_in[2];
    const float* w_red  = (const float*)d_in[3];
    const float* b_red  = (const float*)d_in[4];
    const float* w_span = (const float*)d_in[5];
    const float* b_span = (const float*)d_in[6];
    const float* w_out  = (const float*)d_in[7];
    const float* b_out  = (const float*)d_in[8];
    float* out = (float*)d_out;

    float* kern = (float*)d_ws;                              // 1.18 MB
    unsigned short* x1g = (unsigned short*)(kern + (size_t)BB * 9 * HW); // 16.8 MB bf16
    unsigned short* wtf = x1g + (size_t)BB * CC * HW;        // 32 KB bf16

    build_wtf<<<64, 256, 0, stream>>>(w_red, wtf);
    dw_kern<<<dim3(128, BB), 256, 0, stream>>>(x, w_in, b_in, wtf, b_red,
                                               w_span, b_span, kern, x1g);
    invol_dw<<<dim3(CC, BB), 256, 0, stream>>>(x1g, kern, w_out, b_out, out);
}